// Round 5
// baseline (87.213 us; speedup 1.0000x reference)
//
#include <hip/hip_runtime.h>

typedef _Float16 h2 __attribute__((ext_vector_type(2)));

#define IH 512
#define IW 512
#define OH 502
#define OW 502
#define NIMG 48
#define ROWS 16
#define NSTRIP 32                 // 32*16 = 512 >= 502
#define NBLK (NSTRIP * NIMG)      // 1536
#define PADW 524                  // half2 words per rowbuf row (512 + halo pad)
#define LASTS 12                  // pair-steps S = 0..12 (26 input rows)
#define C1V 1.0e-4f
#define C2V 9.0e-4f

// gaussian(win=11, sigma=1.5), normalized
constexpr float GFc[11] = {
    0.00102838f, 0.00759876f, 0.03600078f, 0.10936070f, 0.21300554f,
    0.26601173f, 0.21300554f, 0.10936070f, 0.03600078f, 0.00759876f,
    0.00102838f};

// cvt_pkrtz returns __fp16-vec; bit-cast to our _Float16-vec h2 (same layout)
static __device__ __forceinline__ h2 pkrtz(float a, float b) {
    return __builtin_bit_cast(h2, __builtin_amdgcn_cvt_pkrtz(a, b));
}

struct Pre {  // pipelined loads for one pair-step
    float a2, a3;   // yt col c,   rows ir+1, ir+2
    float b2, b3;   // yt col c-1, rows ir+1, ir+2
    float d2, d3;   // yt col c+1, rows ir+1, ir+2
    float e0, e1;   // yp col c,   rows ir,   ir+1
};

struct __align__(8) H22 { h2 x, y; };

// horizontal 11-tap blur (packed row-pair) + SSIM for 4 output rows
__device__ __forceinline__ void hphase(const h2 (*rbp)[5][PADW], int orow0,
                                       int tid, const h2 (&gh)[11], float& lsum) {
    const int rbrow = tid >> 8;          // 0..1 (pair-row within phase)
    const int c0 = (tid & 255) << 1;     // even output col base 0..510
    float ov[5][4];                      // [q][col*2 + row]
#pragma unroll
    for (int q = 0; q < 5; q++) {
        const h2* rowp = &rbp[rbrow][q][c0];
        h2 w[12];
#pragma unroll
        for (int u = 0; u < 6; u++) {
            H22 t = *(const H22*)(rowp + 2 * u);   // 8B-aligned LDS loads
            w[2 * u] = t.x; w[2 * u + 1] = t.y;
        }
        h2 s0 = gh[0] * w[0];
        h2 s1 = gh[0] * w[1];
#pragma unroll
        for (int k = 1; k < 11; k++) { s0 += gh[k] * w[k]; s1 += gh[k] * w[k + 1]; }
        ov[q][0] = (float)s0.x; ov[q][1] = (float)s0.y;
        ov[q][2] = (float)s1.x; ov[q][3] = (float)s1.y;
    }
    const int grb = orow0 + (rbrow << 1);
#pragma unroll
    for (int cl = 0; cl < 2; cl++) {
#pragma unroll
        for (int rw = 0; rw < 2; rw++) {
            const int gr = grb + rw, gc = c0 + cl;
            if (gr < OH && gc < OW) {
                const int e = cl * 2 + rw;
                float mu1 = ov[0][e], mu2 = ov[1][e];
                float exx = ov[2][e], eyy = ov[3][e], exy = ov[4][e];
                float mu1s = mu1 * mu1, mu2s = mu2 * mu2, mu12 = mu1 * mu2;
                float s1v = exx - mu1s, s2v = eyy - mu2s, s12 = exy - mu12;
                float num = (2.f * mu12 + C1V) * (2.f * s12 + C2V);
                float den = (mu1s + mu2s + C1V) * (s1v + s2v + C2V);
                lsum += num * __builtin_amdgcn_rcpf(den);
            }
        }
    }
}

// one pair-step: input rows ir = O0+2S, ir+1 (depth-2 prefetch: preA/preB)
template <int S>
__device__ __forceinline__ void stepf(
    float (&acc)[12][5], float& a0, float& a1, float& b1, float& d1,
    Pre& preA, Pre& preB,
    const float* __restrict__ ytc, const float* __restrict__ ytcm,
    const float* __restrict__ ytcp, const float* __restrict__ ypc,
    int O0, bool cgt0, bool clt511,
    const h2 (&rp)[10], const h2 (&gh)[11], float g0s, float g10s,
    h2 (*rbuf)[2][5][PADW], int c, int tid, float& lsum) {
    Pre cur;
    if constexpr ((S & 1) == 0) cur = preA; else cur = preB;
    // ---- issue loads for step S+2 into the buffer just freed ----
    auto issue = [&](Pre& dst) {
        int r1 = O0 + 2 * S + 5; r1 = r1 > (IH - 1) ? (IH - 1) : r1;
        int r2 = O0 + 2 * S + 6; r2 = r2 > (IH - 1) ? (IH - 1) : r2;
        int rE = O0 + 2 * S + 4; rE = rE > (IH - 1) ? (IH - 1) : rE;
        dst.a2 = ytc[(size_t)r1 * IW];  dst.a3 = ytc[(size_t)r2 * IW];
        dst.b2 = ytcm[(size_t)r1 * IW]; dst.b3 = ytcm[(size_t)r2 * IW];
        dst.d2 = ytcp[(size_t)r1 * IW]; dst.d3 = ytcp[(size_t)r2 * IW];
        dst.e0 = ypc[(size_t)rE * IW];  dst.e1 = ypc[(size_t)r1 * IW];
    };
    if constexpr (S + 2 <= LASTS) {
        if constexpr ((S & 1) == 0) issue(preA); else issue(preB);
    }
    // ---- edge-enhance rows ir, ir+1 ----
    float lf0 = cgt0 ? b1 : 0.f;
    float rt0 = clt511 ? d1 : 0.f;
    float lf1 = cgt0 ? cur.b2 : 0.f;
    float rt1 = clt511 ? cur.d2 : 0.f;
    float xr0 = a0 + cur.a2 + lf0 + rt0 - 4.f * a1;
    float xr1 = a1 + cur.a3 + lf1 + rt1 - 4.f * cur.a2;
    float pr0[5] = {xr0, cur.e0, xr0 * xr0, cur.e0 * cur.e0, xr0 * cur.e0};
    float pr1[5] = {xr1, cur.e1, xr1 * xr1, cur.e1 * cur.e1, xr1 * cur.e1};
    h2 pk[5];
#pragma unroll
    for (int q = 0; q < 5; q++) pk[q] = pkrtz(pr0[q], pr1[q]);
    // ---- vertical ring: 2 taps per live output via fdot2 ----
    constexpr int RLO = (2 * S - 10 < 0) ? 0 : (2 * S - 10);
    constexpr int RHI = (2 * S + 1 > ROWS - 1) ? (ROWS - 1) : (2 * S + 1);
#pragma unroll
    for (int rel = RLO; rel <= RHI; ++rel) {
        const int k0 = 2 * S - rel;       // constant after unroll
        const int sl = rel % 12;
#pragma unroll
        for (int q = 0; q < 5; q++) {
            if (k0 == -1)
                acc[sl][q] = g0s * pr1[q];
            else if (k0 == 0)
                acc[sl][q] = __builtin_amdgcn_fdot2(rp[0], pk[q], 0.f, false);
            else if (k0 <= 9)
                acc[sl][q] = __builtin_amdgcn_fdot2(rp[k0], pk[q], acc[sl][q], false);
            else
                acc[sl][q] = fmaf(g10s, pr0[q], acc[sl][q]);
        }
    }
    // ---- carries ----
    a0 = cur.a2; a1 = cur.a3; b1 = cur.b3; d1 = cur.d3;
    // ---- emit completed row-pair (rel 2S-10, 2S-9) as packed half2 ----
    if constexpr (S >= 5) {
        constexpr int p2 = S - 5;
        constexpr int buf = (p2 >> 1) & 1;
        constexpr int sl2 = p2 & 1;
        constexpr int q0 = (2 * S - 10) % 12;
        constexpr int q1 = (2 * S - 9) % 12;
#pragma unroll
        for (int q = 0; q < 5; q++)
            rbuf[buf][sl2][q][c] = pkrtz(acc[q0][q], acc[q1][q]);
    }
    // ---- phase: single barrier (double-buffered rowbuf) ----
    if constexpr (S >= 6 && (S % 2) == 0) {
        __syncthreads();
        constexpr int buf = ((S - 5) >> 1) & 1;
        hphase(rbuf[buf], O0 + 2 * (S - 6), tid, gh, lsum);
    }
}

template <int S, typename... A>
__device__ __forceinline__ void run_steps(A&... a) {
    stepf<S>(a...);
    if constexpr (S < LASTS) run_steps<S + 1>(a...);
}

__global__ __launch_bounds__(512, 4) void ssim_stream(const float* __restrict__ yt,
                                                      const float* __restrict__ yp,
                                                      float* __restrict__ partial) {
    __shared__ __align__(16) h2 rbuf[2][2][5][PADW];   // ~41.9 KB
    __shared__ float wred[8];

    const int tid = threadIdx.x;
    const int c = tid;
    const int strip = blockIdx.x;
    const int img = blockIdx.y;
    const int O0 = strip * ROWS;
    const size_t ib = (size_t)img * (IH * IW);
    const float* ytb = yt + ib;
    const float* ypb = yp + ib;

    const int cm = c > 0 ? c - 1 : 0;
    const int cp = c < (IW - 1) ? c + 1 : (IW - 1);
    const bool cgt0 = c > 0, clt511 = c < (IW - 1);
    const float* ytc = ytb + c;
    const float* ytcm = ytb + cm;
    const float* ytcp = ytb + cp;
    const float* ypc = ypb + c;

    // weights in registers (compile-time folded)
    h2 rp[10], gh[11];
#pragma unroll
    for (int k = 0; k < 10; k++) rp[k] = h2{(_Float16)GFc[k], (_Float16)GFc[k + 1]};
#pragma unroll
    for (int k = 0; k < 11; k++) gh[k] = h2{(_Float16)GFc[k], (_Float16)GFc[k]};
    const float g0s = GFc[0], g10s = GFc[10];

    // prologue: carries + first TWO steps' loads (depth-2 pipeline)
    float a0, a1, b1, d1;
    {
        int rm1 = O0 > 0 ? O0 - 1 : 0;
        float a0v = ytc[(size_t)rm1 * IW];
        a1 = ytc[(size_t)O0 * IW];
        b1 = ytcm[(size_t)O0 * IW];
        d1 = ytcp[(size_t)O0 * IW];
        a0 = (O0 > 0) ? a0v : 0.f;
    }
    Pre preA, preB;
    {   // step 0: rows O0+1, O0+2; e rows O0, O0+1
        int r1 = O0 + 1, r2 = O0 + 2;
        preA.a2 = ytc[(size_t)r1 * IW];  preA.a3 = ytc[(size_t)r2 * IW];
        preA.b2 = ytcm[(size_t)r1 * IW]; preA.b3 = ytcm[(size_t)r2 * IW];
        preA.d2 = ytcp[(size_t)r1 * IW]; preA.d3 = ytcp[(size_t)r2 * IW];
        preA.e0 = ypc[(size_t)O0 * IW];  preA.e1 = ypc[(size_t)r1 * IW];
    }
    {   // step 1: rows O0+3, O0+4; e rows O0+2, O0+3
        int r1 = O0 + 3, r2 = O0 + 4;
        preB.a2 = ytc[(size_t)r1 * IW];  preB.a3 = ytc[(size_t)r2 * IW];
        preB.b2 = ytcm[(size_t)r1 * IW]; preB.b3 = ytcm[(size_t)r2 * IW];
        preB.d2 = ytcp[(size_t)r1 * IW]; preB.d3 = ytcp[(size_t)r2 * IW];
        preB.e0 = ypc[(size_t)(O0 + 2) * IW]; preB.e1 = ypc[(size_t)r1 * IW];
    }

    float acc[12][5];   // ring; every slot is init-on-first-tap
    float lsum = 0.f;

    run_steps<0>(acc, a0, a1, b1, d1, preA, preB, ytc, ytcm, ytcp, ypc, O0,
                 cgt0, clt511, rp, gh, g0s, g10s, rbuf, c, tid, lsum);

#pragma unroll
    for (int off = 32; off > 0; off >>= 1) lsum += __shfl_down(lsum, off);
    if ((tid & 63) == 0) wred[tid >> 6] = lsum;
    __syncthreads();
    if (tid == 0) {
        float s = 0.f;
#pragma unroll
        for (int w = 0; w < 8; w++) s += wred[w];
        partial[strip + NSTRIP * img] = s;
    }
}

__global__ __launch_bounds__(256) void ssim_final(const float* __restrict__ partial,
                                                  float* __restrict__ out) {
    __shared__ double wred[4];
    double s = 0.0;
    for (int i = threadIdx.x; i < NBLK; i += 256) s += (double)partial[i];
#pragma unroll
    for (int off = 32; off > 0; off >>= 1) s += __shfl_down(s, off);
    if ((threadIdx.x & 63) == 0) wred[threadIdx.x >> 6] = s;
    __syncthreads();
    if (threadIdx.x == 0) {
        double tot = wred[0] + wred[1] + wred[2] + wred[3];
        out[0] = (float)(1.0 - tot / (double)((long long)OH * OW * NIMG));
    }
}

extern "C" void kernel_launch(void* const* d_in, const int* in_sizes, int n_in,
                              void* d_out, int out_size, void* d_ws, size_t ws_size,
                              hipStream_t stream) {
    const float* yt = (const float*)d_in[0];
    const float* yp = (const float*)d_in[1];
    float* out = (float*)d_out;
    float* partial = (float*)d_ws;   // NBLK floats = 6 KB

    dim3 grid(NSTRIP, NIMG);
    hipLaunchKernelGGL(ssim_stream, grid, dim3(512), 0, stream, yt, yp, partial);
    hipLaunchKernelGGL(ssim_final, dim3(1), dim3(256), 0, stream, partial, out);
}

// Round 6
// 60.329 us; speedup vs baseline: 1.4456x; 1.4456x over previous
//
#include <hip/hip_runtime.h>

typedef _Float16 h2 __attribute__((ext_vector_type(2)));

#define IH 512
#define IW 512
#define OH 502
#define OW 502
#define NIMG 48
#define ROWS 32
#define NSTRIP 16                 // 16*32 = 512 >= 502
#define NBLK (NSTRIP * NIMG)      // 768
#define PADW 524                  // half2 words per rowbuf row (512 + halo pad)
#define LASTS 20                  // pair-steps S = 0..20 (42 input rows)
#define C1V 1.0e-4f
#define C2V 9.0e-4f

// gaussian(win=11, sigma=1.5), normalized
constexpr float GFc[11] = {
    0.00102838f, 0.00759876f, 0.03600078f, 0.10936070f, 0.21300554f,
    0.26601173f, 0.21300554f, 0.10936070f, 0.03600078f, 0.00759876f,
    0.00102838f};

// cvt_pkrtz returns __fp16-vec; bit-cast to our _Float16-vec h2 (same layout)
static __device__ __forceinline__ h2 pkrtz(float a, float b) {
    return __builtin_bit_cast(h2, __builtin_amdgcn_cvt_pkrtz(a, b));
}

struct Pre {  // pipelined loads for one pair-step
    float a2, a3;   // yt col c,   rows ir+1, ir+2
    float b2, b3;   // yt col c-1, rows ir+1, ir+2
    float d2, d3;   // yt col c+1, rows ir+1, ir+2
    float e0, e1;   // yp col c,   rows ir,   ir+1
};

struct __align__(8) H22 { h2 x, y; };

// horizontal 11-tap blur (packed row-pair) + SSIM for 4 output rows
__device__ __forceinline__ void hphase(const h2 (*rbp)[5][PADW], int orow0,
                                       int tid, const h2 (&gh)[11], float& lsum) {
    const int rbrow = tid >> 8;          // 0..1 (pair-row within phase)
    const int c0 = (tid & 255) << 1;     // even output col base 0..510
    float ov[5][4];                      // [q][col*2 + row]
#pragma unroll
    for (int q = 0; q < 5; q++) {
        const h2* rowp = &rbp[rbrow][q][c0];
        h2 w[12];
#pragma unroll
        for (int u = 0; u < 6; u++) {
            H22 t = *(const H22*)(rowp + 2 * u);   // 8B-aligned LDS loads
            w[2 * u] = t.x; w[2 * u + 1] = t.y;
        }
        h2 s0 = gh[0] * w[0];
        h2 s1 = gh[0] * w[1];
#pragma unroll
        for (int k = 1; k < 11; k++) { s0 += gh[k] * w[k]; s1 += gh[k] * w[k + 1]; }
        ov[q][0] = (float)s0.x; ov[q][1] = (float)s0.y;
        ov[q][2] = (float)s1.x; ov[q][3] = (float)s1.y;
    }
    const int grb = orow0 + (rbrow << 1);
#pragma unroll
    for (int cl = 0; cl < 2; cl++) {
#pragma unroll
        for (int rw = 0; rw < 2; rw++) {
            const int gr = grb + rw, gc = c0 + cl;
            if (gr < OH && gc < OW) {
                const int e = cl * 2 + rw;
                float mu1 = ov[0][e], mu2 = ov[1][e];
                float exx = ov[2][e], eyy = ov[3][e], exy = ov[4][e];
                float mu1s = mu1 * mu1, mu2s = mu2 * mu2, mu12 = mu1 * mu2;
                float s1v = exx - mu1s, s2v = eyy - mu2s, s12 = exy - mu12;
                float num = (2.f * mu12 + C1V) * (2.f * s12 + C2V);
                float den = (mu1s + mu2s + C1V) * (s1v + s2v + C2V);
                lsum += num * __builtin_amdgcn_rcpf(den);
            }
        }
    }
}

// one pair-step: input rows ir = O0+2S, ir+1 (depth-2 prefetch: preA/preB)
template <int S>
__device__ __forceinline__ void stepf(
    float (&acc)[12][5], float& a0, float& a1, float& b1, float& d1,
    Pre& preA, Pre& preB,
    const float* __restrict__ ytc, const float* __restrict__ ytcm,
    const float* __restrict__ ytcp, const float* __restrict__ ypc,
    int O0, bool cgt0, bool clt511,
    const h2 (&rp)[10], const h2 (&gh)[11], float g0s, float g10s,
    h2 (*rbuf)[2][5][PADW], int c, int tid, float& lsum) {
    Pre cur;
    if constexpr ((S & 1) == 0) cur = preA; else cur = preB;
    // ---- issue loads for step S+2 into the buffer just freed ----
    auto issue = [&](Pre& dst) {
        int r1 = O0 + 2 * S + 5; r1 = r1 > (IH - 1) ? (IH - 1) : r1;
        int r2 = O0 + 2 * S + 6; r2 = r2 > (IH - 1) ? (IH - 1) : r2;
        int rE = O0 + 2 * S + 4; rE = rE > (IH - 1) ? (IH - 1) : rE;
        dst.a2 = ytc[(size_t)r1 * IW];  dst.a3 = ytc[(size_t)r2 * IW];
        dst.b2 = ytcm[(size_t)r1 * IW]; dst.b3 = ytcm[(size_t)r2 * IW];
        dst.d2 = ytcp[(size_t)r1 * IW]; dst.d3 = ytcp[(size_t)r2 * IW];
        dst.e0 = ypc[(size_t)rE * IW];  dst.e1 = ypc[(size_t)r1 * IW];
    };
    if constexpr (S + 2 <= LASTS) {
        if constexpr ((S & 1) == 0) issue(preA); else issue(preB);
    }
    // ---- edge-enhance rows ir, ir+1 ----
    float lf0 = cgt0 ? b1 : 0.f;
    float rt0 = clt511 ? d1 : 0.f;
    float lf1 = cgt0 ? cur.b2 : 0.f;
    float rt1 = clt511 ? cur.d2 : 0.f;
    float xr0 = a0 + cur.a2 + lf0 + rt0 - 4.f * a1;
    float xr1 = a1 + cur.a3 + lf1 + rt1 - 4.f * cur.a2;
    float pr0[5] = {xr0, cur.e0, xr0 * xr0, cur.e0 * cur.e0, xr0 * cur.e0};
    float pr1[5] = {xr1, cur.e1, xr1 * xr1, cur.e1 * cur.e1, xr1 * cur.e1};
    h2 pk[5];
#pragma unroll
    for (int q = 0; q < 5; q++) pk[q] = pkrtz(pr0[q], pr1[q]);
    // ---- vertical ring: 2 taps per live output via fdot2 ----
    constexpr int RLO = (2 * S - 10 < 0) ? 0 : (2 * S - 10);
    constexpr int RHI = (2 * S + 1 > ROWS - 1) ? (ROWS - 1) : (2 * S + 1);
#pragma unroll
    for (int rel = RLO; rel <= RHI; ++rel) {
        const int k0 = 2 * S - rel;       // constant after unroll
        const int sl = rel % 12;
#pragma unroll
        for (int q = 0; q < 5; q++) {
            if (k0 == -1)
                acc[sl][q] = g0s * pr1[q];
            else if (k0 == 0)
                acc[sl][q] = __builtin_amdgcn_fdot2(rp[0], pk[q], 0.f, false);
            else if (k0 <= 9)
                acc[sl][q] = __builtin_amdgcn_fdot2(rp[k0], pk[q], acc[sl][q], false);
            else
                acc[sl][q] = fmaf(g10s, pr0[q], acc[sl][q]);
        }
    }
    // ---- carries ----
    a0 = cur.a2; a1 = cur.a3; b1 = cur.b3; d1 = cur.d3;
    // ---- emit completed row-pair (rel 2S-10, 2S-9) as packed half2 ----
    if constexpr (S >= 5) {
        constexpr int p2 = S - 5;
        constexpr int buf = (p2 >> 1) & 1;
        constexpr int sl2 = p2 & 1;
        constexpr int q0 = (2 * S - 10) % 12;
        constexpr int q1 = (2 * S - 9) % 12;
#pragma unroll
        for (int q = 0; q < 5; q++)
            rbuf[buf][sl2][q][c] = pkrtz(acc[q0][q], acc[q1][q]);
    }
    // ---- phase: barrier WITHOUT vmcnt drain (prefetches stay in flight) ----
    // Own ds_writes flushed (lgkmcnt), then s_barrier; LDS has no caches so
    // writes are visible to readers after the barrier. Prefetch global loads
    // target wave-private VGPRs and need no cross-thread ordering here.
    if constexpr (S >= 6 && (S % 2) == 0) {
        asm volatile("s_waitcnt lgkmcnt(0)\n\ts_barrier" ::: "memory");
        constexpr int buf = ((S - 5) >> 1) & 1;
        hphase(rbuf[buf], O0 + 2 * (S - 6), tid, gh, lsum);
    }
}

template <int S, typename... A>
__device__ __forceinline__ void run_steps(A&... a) {
    stepf<S>(a...);
    if constexpr (S < LASTS) run_steps<S + 1>(a...);
}

__global__ __launch_bounds__(512) void ssim_stream(const float* __restrict__ yt,
                                                   const float* __restrict__ yp,
                                                   float* __restrict__ partial) {
    __shared__ __align__(16) h2 rbuf[2][2][5][PADW];   // ~41.9 KB
    __shared__ float wred[8];

    const int tid = threadIdx.x;
    const int c = tid;
    const int strip = blockIdx.x;
    const int img = blockIdx.y;
    const int O0 = strip * ROWS;
    const size_t ib = (size_t)img * (IH * IW);
    const float* ytb = yt + ib;
    const float* ypb = yp + ib;

    const int cm = c > 0 ? c - 1 : 0;
    const int cp = c < (IW - 1) ? c + 1 : (IW - 1);
    const bool cgt0 = c > 0, clt511 = c < (IW - 1);
    const float* ytc = ytb + c;
    const float* ytcm = ytb + cm;
    const float* ytcp = ytb + cp;
    const float* ypc = ypb + c;

    // weights in registers (compile-time folded)
    h2 rp[10], gh[11];
#pragma unroll
    for (int k = 0; k < 10; k++) rp[k] = h2{(_Float16)GFc[k], (_Float16)GFc[k + 1]};
#pragma unroll
    for (int k = 0; k < 11; k++) gh[k] = h2{(_Float16)GFc[k], (_Float16)GFc[k]};
    const float g0s = GFc[0], g10s = GFc[10];

    // prologue: carries + first TWO steps' loads (depth-2 pipeline)
    float a0, a1, b1, d1;
    {
        int rm1 = O0 > 0 ? O0 - 1 : 0;
        float a0v = ytc[(size_t)rm1 * IW];
        a1 = ytc[(size_t)O0 * IW];
        b1 = ytcm[(size_t)O0 * IW];
        d1 = ytcp[(size_t)O0 * IW];
        a0 = (O0 > 0) ? a0v : 0.f;
    }
    Pre preA, preB;
    {   // step 0: rows O0+1, O0+2; e rows O0, O0+1
        int r1 = O0 + 1, r2 = O0 + 2;
        preA.a2 = ytc[(size_t)r1 * IW];  preA.a3 = ytc[(size_t)r2 * IW];
        preA.b2 = ytcm[(size_t)r1 * IW]; preA.b3 = ytcm[(size_t)r2 * IW];
        preA.d2 = ytcp[(size_t)r1 * IW]; preA.d3 = ytcp[(size_t)r2 * IW];
        preA.e0 = ypc[(size_t)O0 * IW];  preA.e1 = ypc[(size_t)r1 * IW];
    }
    {   // step 1: rows O0+3, O0+4; e rows O0+2, O0+3
        int r1 = O0 + 3, r2 = O0 + 4;
        preB.a2 = ytc[(size_t)r1 * IW];  preB.a3 = ytc[(size_t)r2 * IW];
        preB.b2 = ytcm[(size_t)r1 * IW]; preB.b3 = ytcm[(size_t)r2 * IW];
        preB.d2 = ytcp[(size_t)r1 * IW]; preB.d3 = ytcp[(size_t)r2 * IW];
        preB.e0 = ypc[(size_t)(O0 + 2) * IW]; preB.e1 = ypc[(size_t)r1 * IW];
    }

    float acc[12][5];   // ring; every slot is init-on-first-tap
    float lsum = 0.f;

    run_steps<0>(acc, a0, a1, b1, d1, preA, preB, ytc, ytcm, ytcp, ypc, O0,
                 cgt0, clt511, rp, gh, g0s, g10s, rbuf, c, tid, lsum);

#pragma unroll
    for (int off = 32; off > 0; off >>= 1) lsum += __shfl_down(lsum, off);
    if ((tid & 63) == 0) wred[tid >> 6] = lsum;
    __syncthreads();
    if (tid == 0) {
        float s = 0.f;
#pragma unroll
        for (int w = 0; w < 8; w++) s += wred[w];
        partial[strip + NSTRIP * img] = s;
    }
}

__global__ __launch_bounds__(256) void ssim_final(const float* __restrict__ partial,
                                                  float* __restrict__ out) {
    __shared__ double wred[4];
    double s = 0.0;
    for (int i = threadIdx.x; i < NBLK; i += 256) s += (double)partial[i];
#pragma unroll
    for (int off = 32; off > 0; off >>= 1) s += __shfl_down(s, off);
    if ((threadIdx.x & 63) == 0) wred[threadIdx.x >> 6] = s;
    __syncthreads();
    if (threadIdx.x == 0) {
        double tot = wred[0] + wred[1] + wred[2] + wred[3];
        out[0] = (float)(1.0 - tot / (double)((long long)OH * OW * NIMG));
    }
}

extern "C" void kernel_launch(void* const* d_in, const int* in_sizes, int n_in,
                              void* d_out, int out_size, void* d_ws, size_t ws_size,
                              hipStream_t stream) {
    const float* yt = (const float*)d_in[0];
    const float* yp = (const float*)d_in[1];
    float* out = (float*)d_out;
    float* partial = (float*)d_ws;   // NBLK floats = 3 KB

    dim3 grid(NSTRIP, NIMG);
    hipLaunchKernelGGL(ssim_stream, grid, dim3(512), 0, stream, yt, yp, partial);
    hipLaunchKernelGGL(ssim_final, dim3(1), dim3(256), 0, stream, partial, out);
}

// Round 7
// 59.519 us; speedup vs baseline: 1.4653x; 1.0136x over previous
//
#include <hip/hip_runtime.h>

typedef _Float16 h2 __attribute__((ext_vector_type(2)));

#define IH 512
#define IW 512
#define OH 502
#define OW 502
#define NIMG 48
#define ROWS 32
#define NSTRIP 16                 // 16*32 = 512 >= 502
#define NBLK (NSTRIP * NIMG)      // 768
#define PADW 524                  // half2 words per rowbuf row (512 + halo pad)
#define LASTS 20                  // pair-steps S = 0..20 (42 input rows)
#define C1V 1.0e-4f
#define C2V 9.0e-4f

// gaussian(win=11, sigma=1.5), normalized
constexpr float GFc[11] = {
    0.00102838f, 0.00759876f, 0.03600078f, 0.10936070f, 0.21300554f,
    0.26601173f, 0.21300554f, 0.10936070f, 0.03600078f, 0.00759876f,
    0.00102838f};

// cvt_pkrtz returns __fp16-vec; bit-cast to our _Float16-vec h2 (same layout)
static __device__ __forceinline__ h2 pkrtz(float a, float b) {
    return __builtin_bit_cast(h2, __builtin_amdgcn_cvt_pkrtz(a, b));
}

struct Pre {  // pipelined loads for one pair-step
    float a2, a3;   // yt col c,   rows 2X+1, 2X+2
    float b2, b3;   // yt col c-1, rows 2X+1, 2X+2
    float d2, d3;   // yt col c+1, rows 2X+1, 2X+2
    float e0, e1;   // yp col c,   rows 2X,   2X+1
};

struct __align__(8) H22 { h2 x, y; };

// deferred H-phase state carried across one step in registers
struct HS {
    float ov[3][4];   // q=0..2 blurred (mu1, mu2, E[xx]) for this thread's 4 px
    h2 w3[12];        // raw LDS words for q=3 (E[yy])
    h2 w4[12];        // raw LDS words for q=4 (E[xy])
};

// phase part A (at barrier): issue ALL 30 LDS loads, compute q=0..2 only
__device__ __forceinline__ void hphaseA(const h2 (*rbp)[5][PADW], int tid,
                                        const h2 (&gh)[11], HS& hs) {
    const int rbrow = tid >> 8;          // 0..1 (pair-row within phase)
    const int c0 = (tid & 255) << 1;     // even output col base 0..510
#pragma unroll
    for (int q = 0; q < 5; q++) {
        const h2* rowp = &rbp[rbrow][q][c0];
        h2 w[12];
#pragma unroll
        for (int u = 0; u < 6; u++) {
            H22 t = *(const H22*)(rowp + 2 * u);   // 8B-aligned LDS loads
            w[2 * u] = t.x; w[2 * u + 1] = t.y;
        }
        if (q < 3) {
            h2 s0 = gh[0] * w[0];
            h2 s1 = gh[0] * w[1];
#pragma unroll
            for (int k = 1; k < 11; k++) { s0 += gh[k] * w[k]; s1 += gh[k] * w[k + 1]; }
            hs.ov[q][0] = (float)s0.x; hs.ov[q][1] = (float)s0.y;
            hs.ov[q][2] = (float)s1.x; hs.ov[q][3] = (float)s1.y;
        } else if (q == 3) {
#pragma unroll
            for (int u = 0; u < 12; u++) hs.w3[u] = w[u];
        } else {
#pragma unroll
            for (int u = 0; u < 12; u++) hs.w4[u] = w[u];
        }
    }
}

// phase part B (one step later, register-only): q=3,4 blur + SSIM
__device__ __forceinline__ void hphaseB(const HS& hs, int orow0, int tid,
                                        const h2 (&gh)[11], float& lsum) {
    const int rbrow = tid >> 8;
    const int c0 = (tid & 255) << 1;
    float ov3[4], ov4[4];
    {
        h2 s0 = gh[0] * hs.w3[0];
        h2 s1 = gh[0] * hs.w3[1];
#pragma unroll
        for (int k = 1; k < 11; k++) { s0 += gh[k] * hs.w3[k]; s1 += gh[k] * hs.w3[k + 1]; }
        ov3[0] = (float)s0.x; ov3[1] = (float)s0.y;
        ov3[2] = (float)s1.x; ov3[3] = (float)s1.y;
    }
    {
        h2 s0 = gh[0] * hs.w4[0];
        h2 s1 = gh[0] * hs.w4[1];
#pragma unroll
        for (int k = 1; k < 11; k++) { s0 += gh[k] * hs.w4[k]; s1 += gh[k] * hs.w4[k + 1]; }
        ov4[0] = (float)s0.x; ov4[1] = (float)s0.y;
        ov4[2] = (float)s1.x; ov4[3] = (float)s1.y;
    }
    const int grb = orow0 + (rbrow << 1);
#pragma unroll
    for (int cl = 0; cl < 2; cl++) {
#pragma unroll
        for (int rw = 0; rw < 2; rw++) {
            const int gr = grb + rw, gc = c0 + cl;
            if (gr < OH && gc < OW) {
                const int e = cl * 2 + rw;
                float mu1 = hs.ov[0][e], mu2 = hs.ov[1][e];
                float exx = hs.ov[2][e], eyy = ov3[e], exy = ov4[e];
                float mu1s = mu1 * mu1, mu2s = mu2 * mu2, mu12 = mu1 * mu2;
                float s1v = exx - mu1s, s2v = eyy - mu2s, s12 = exy - mu12;
                float num = (2.f * mu12 + C1V) * (2.f * s12 + C2V);
                float den = (mu1s + mu2s + C1V) * (s1v + s2v + C2V);
                lsum += num * __builtin_amdgcn_rcpf(den);
            }
        }
    }
}

// one pair-step: input rows ir = O0+2S, ir+1 (depth-3 prefetch: preA/B/C)
template <int S>
__device__ __forceinline__ void stepf(
    float (&acc)[12][5], float& a0, float& a1, float& b1, float& d1,
    Pre& preA, Pre& preB, Pre& preC, HS& hs,
    const float* __restrict__ ytc, const float* __restrict__ ytcm,
    const float* __restrict__ ytcp, const float* __restrict__ ypc,
    int O0, bool cgt0, bool clt511,
    const h2 (&rp)[10], const h2 (&gh)[11], float g0s, float g10s,
    h2 (*rbuf)[2][5][PADW], int c, int tid, float& lsum) {
    Pre cur;
    if constexpr (S % 3 == 0) cur = preA;
    else if constexpr (S % 3 == 1) cur = preB;
    else cur = preC;
    // ---- issue loads for step S+3 into the buffer just consumed ----
    auto issue = [&](Pre& dst) {
        int r1 = O0 + 2 * S + 7; r1 = r1 > (IH - 1) ? (IH - 1) : r1;
        int r2 = O0 + 2 * S + 8; r2 = r2 > (IH - 1) ? (IH - 1) : r2;
        int rE = O0 + 2 * S + 6; rE = rE > (IH - 1) ? (IH - 1) : rE;
        dst.a2 = ytc[(size_t)r1 * IW];  dst.a3 = ytc[(size_t)r2 * IW];
        dst.b2 = ytcm[(size_t)r1 * IW]; dst.b3 = ytcm[(size_t)r2 * IW];
        dst.d2 = ytcp[(size_t)r1 * IW]; dst.d3 = ytcp[(size_t)r2 * IW];
        dst.e0 = ypc[(size_t)rE * IW];  dst.e1 = ypc[(size_t)r1 * IW];
    };
    if constexpr (S + 3 <= LASTS) {
        if constexpr (S % 3 == 0) issue(preA);
        else if constexpr (S % 3 == 1) issue(preB);
        else issue(preC);
    }
    // ---- edge-enhance rows ir, ir+1 ----
    float lf0 = cgt0 ? b1 : 0.f;
    float rt0 = clt511 ? d1 : 0.f;
    float lf1 = cgt0 ? cur.b2 : 0.f;
    float rt1 = clt511 ? cur.d2 : 0.f;
    float xr0 = a0 + cur.a2 + lf0 + rt0 - 4.f * a1;
    float xr1 = a1 + cur.a3 + lf1 + rt1 - 4.f * cur.a2;
    float pr0[5] = {xr0, cur.e0, xr0 * xr0, cur.e0 * cur.e0, xr0 * cur.e0};
    float pr1[5] = {xr1, cur.e1, xr1 * xr1, cur.e1 * cur.e1, xr1 * cur.e1};
    h2 pk[5];
#pragma unroll
    for (int q = 0; q < 5; q++) pk[q] = pkrtz(pr0[q], pr1[q]);
    // ---- vertical ring: 2 taps per live output via fdot2 ----
    constexpr int RLO = (2 * S - 10 < 0) ? 0 : (2 * S - 10);
    constexpr int RHI = (2 * S + 1 > ROWS - 1) ? (ROWS - 1) : (2 * S + 1);
#pragma unroll
    for (int rel = RLO; rel <= RHI; ++rel) {
        const int k0 = 2 * S - rel;       // constant after unroll
        const int sl = rel % 12;
#pragma unroll
        for (int q = 0; q < 5; q++) {
            if (k0 == -1)
                acc[sl][q] = g0s * pr1[q];
            else if (k0 == 0)
                acc[sl][q] = __builtin_amdgcn_fdot2(rp[0], pk[q], 0.f, false);
            else if (k0 <= 9)
                acc[sl][q] = __builtin_amdgcn_fdot2(rp[k0], pk[q], acc[sl][q], false);
            else
                acc[sl][q] = fmaf(g10s, pr0[q], acc[sl][q]);
        }
    }
    // ---- carries ----
    a0 = cur.a2; a1 = cur.a3; b1 = cur.b3; d1 = cur.d3;
    // ---- emit completed row-pair (rel 2S-10, 2S-9) as packed half2 ----
    if constexpr (S >= 5) {
        constexpr int p2 = S - 5;
        constexpr int buf = (p2 >> 1) & 1;
        constexpr int sl2 = p2 & 1;
        constexpr int q0 = (2 * S - 10) % 12;
        constexpr int q1 = (2 * S - 9) % 12;
#pragma unroll
        for (int q = 0; q < 5; q++)
            rbuf[buf][sl2][q][c] = pkrtz(acc[q0][q], acc[q1][q]);
    }
    // ---- phase A at even S: barrier (no vmcnt drain) + loads + q<3 math ----
    if constexpr (S >= 6 && (S % 2) == 0) {
        asm volatile("s_waitcnt lgkmcnt(0)\n\ts_barrier" ::: "memory");
        constexpr int buf = ((S - 5) >> 1) & 1;
        hphaseA(rbuf[buf], tid, gh, hs);
    }
    // ---- phase B at odd S: register-only finish of previous phase ----
    if constexpr (S >= 7 && (S % 2) == 1) {
        hphaseB(hs, O0 + 2 * (S - 7), tid, gh, lsum);
    }
}

template <int S, typename... A>
__device__ __forceinline__ void run_steps(A&... a) {
    stepf<S>(a...);
    if constexpr (S < LASTS) run_steps<S + 1>(a...);
}

__global__ __launch_bounds__(512) void ssim_stream(const float* __restrict__ yt,
                                                   const float* __restrict__ yp,
                                                   float* __restrict__ partial) {
    __shared__ __align__(16) h2 rbuf[2][2][5][PADW];   // ~41.9 KB
    __shared__ float wred[8];

    const int tid = threadIdx.x;
    const int c = tid;
    const int strip = blockIdx.x;
    const int img = blockIdx.y;
    const int O0 = strip * ROWS;
    const size_t ib = (size_t)img * (IH * IW);
    const float* ytb = yt + ib;
    const float* ypb = yp + ib;

    const int cm = c > 0 ? c - 1 : 0;
    const int cp = c < (IW - 1) ? c + 1 : (IW - 1);
    const bool cgt0 = c > 0, clt511 = c < (IW - 1);
    const float* ytc = ytb + c;
    const float* ytcm = ytb + cm;
    const float* ytcp = ytb + cp;
    const float* ypc = ypb + c;

    // weights in registers (compile-time folded)
    h2 rp[10], gh[11];
#pragma unroll
    for (int k = 0; k < 10; k++) rp[k] = h2{(_Float16)GFc[k], (_Float16)GFc[k + 1]};
#pragma unroll
    for (int k = 0; k < 11; k++) gh[k] = h2{(_Float16)GFc[k], (_Float16)GFc[k]};
    const float g0s = GFc[0], g10s = GFc[10];

    // prologue: carries + first THREE steps' loads (depth-3 pipeline)
    float a0, a1, b1, d1;
    {
        int rm1 = O0 > 0 ? O0 - 1 : 0;
        float a0v = ytc[(size_t)rm1 * IW];
        a1 = ytc[(size_t)O0 * IW];
        b1 = ytcm[(size_t)O0 * IW];
        d1 = ytcp[(size_t)O0 * IW];
        a0 = (O0 > 0) ? a0v : 0.f;
    }
    Pre preA, preB, preC;
    auto fill = [&](Pre& dst, int X) {
        int r1 = O0 + 2 * X + 1; r1 = r1 > (IH - 1) ? (IH - 1) : r1;
        int r2 = O0 + 2 * X + 2; r2 = r2 > (IH - 1) ? (IH - 1) : r2;
        int rE = O0 + 2 * X;     rE = rE > (IH - 1) ? (IH - 1) : rE;
        dst.a2 = ytc[(size_t)r1 * IW];  dst.a3 = ytc[(size_t)r2 * IW];
        dst.b2 = ytcm[(size_t)r1 * IW]; dst.b3 = ytcm[(size_t)r2 * IW];
        dst.d2 = ytcp[(size_t)r1 * IW]; dst.d3 = ytcp[(size_t)r2 * IW];
        dst.e0 = ypc[(size_t)rE * IW];  dst.e1 = ypc[(size_t)r1 * IW];
    };
    fill(preA, 0);
    fill(preB, 1);
    fill(preC, 2);

    float acc[12][5];   // ring; every slot is init-on-first-tap
    float lsum = 0.f;
    HS hs;

    run_steps<0>(acc, a0, a1, b1, d1, preA, preB, preC, hs, ytc, ytcm, ytcp, ypc,
                 O0, cgt0, clt511, rp, gh, g0s, g10s, rbuf, c, tid, lsum);

    // finish of the last phase (S=20): register-only
    hphaseB(hs, O0 + 2 * (20 - 6), tid, gh, lsum);

#pragma unroll
    for (int off = 32; off > 0; off >>= 1) lsum += __shfl_down(lsum, off);
    if ((tid & 63) == 0) wred[tid >> 6] = lsum;
    __syncthreads();
    if (tid == 0) {
        float s = 0.f;
#pragma unroll
        for (int w = 0; w < 8; w++) s += wred[w];
        partial[strip + NSTRIP * img] = s;
    }
}

__global__ __launch_bounds__(256) void ssim_final(const float* __restrict__ partial,
                                                  float* __restrict__ out) {
    __shared__ double wred[4];
    double s = 0.0;
    for (int i = threadIdx.x; i < NBLK; i += 256) s += (double)partial[i];
#pragma unroll
    for (int off = 32; off > 0; off >>= 1) s += __shfl_down(s, off);
    if ((threadIdx.x & 63) == 0) wred[threadIdx.x >> 6] = s;
    __syncthreads();
    if (threadIdx.x == 0) {
        double tot = wred[0] + wred[1] + wred[2] + wred[3];
        out[0] = (float)(1.0 - tot / (double)((long long)OH * OW * NIMG));
    }
}

extern "C" void kernel_launch(void* const* d_in, const int* in_sizes, int n_in,
                              void* d_out, int out_size, void* d_ws, size_t ws_size,
                              hipStream_t stream) {
    const float* yt = (const float*)d_in[0];
    const float* yp = (const float*)d_in[1];
    float* out = (float*)d_out;
    float* partial = (float*)d_ws;   // NBLK floats = 3 KB

    dim3 grid(NSTRIP, NIMG);
    hipLaunchKernelGGL(ssim_stream, grid, dim3(512), 0, stream, yt, yp, partial);
    hipLaunchKernelGGL(ssim_final, dim3(1), dim3(256), 0, stream, partial, out);
}

// Round 8
// 55.659 us; speedup vs baseline: 1.5669x; 1.0693x over previous
//
#include <hip/hip_runtime.h>

typedef _Float16 h2 __attribute__((ext_vector_type(2)));

#define IH 512
#define IW 512
#define OH 502
#define OW 502
#define NIMG 48
#define ROWS 32
#define NSTRIP 16                 // 16*32 = 512 >= 502
#define NBLK (NSTRIP * NIMG)      // 768
#define PADW 524                  // h2 words per rowbuf row; 524*4B = 2096 % 16 == 0
#define LASTS 20                  // pair-steps S = 0..20 (42 input rows)
#define C1V 1.0e-4f
#define C2V 9.0e-4f

// gaussian(win=11, sigma=1.5), normalized
constexpr float GFc[11] = {
    0.00102838f, 0.00759876f, 0.03600078f, 0.10936070f, 0.21300554f,
    0.26601173f, 0.21300554f, 0.10936070f, 0.03600078f, 0.00759876f,
    0.00102838f};

// cvt_pkrtz returns __fp16-vec; bit-cast to our _Float16-vec h2 (same layout)
static __device__ __forceinline__ h2 pkrtz(float a, float b) {
    return __builtin_bit_cast(h2, __builtin_amdgcn_cvt_pkrtz(a, b));
}

struct Pre {  // pipelined loads for one pair-step
    float a2, a3;   // yt col c,   rows 2X+1, 2X+2
    float b2, b3;   // yt col c-1, rows 2X+1, 2X+2
    float d2, d3;   // yt col c+1, rows 2X+1, 2X+2
    float e0, e1;   // yp col c,   rows 2X,   2X+1
};

struct __align__(16) H4  { h2 a, b, c, d; };
struct __align__(8)  H22 { h2 x, y; };

// 8-row H-phase: thread -> (row-pair rp = tid>>7, out cols cb..cb+3).
// Reads 14 aligned words per q (3x b128 + 1x b64), 11-tap packed blur, SSIM.
__device__ __forceinline__ void hphase8(const h2 (*rb)[5][PADW], int orow0,
                                        int tid, const h2 (&gh)[11], float& lsum) {
    const int rp = tid >> 7;             // pair-slot 0..3
    const int cb = (tid & 127) << 2;     // out-col base 0..508 (16B aligned)
    h2 ov[5][4];                         // packed (row-even, row-odd) per q, col
#pragma unroll
    for (int q = 0; q < 5; q++) {
        const h2* rowp = &rb[rp][q][cb];
        H4  t0 = *(const H4*)(rowp);
        H4  t1 = *(const H4*)(rowp + 4);
        H4  t2 = *(const H4*)(rowp + 8);
        H22 t3 = *(const H22*)(rowp + 12);
        h2 w[14] = {t0.a, t0.b, t0.c, t0.d, t1.a, t1.b, t1.c, t1.d,
                    t2.a, t2.b, t2.c, t2.d, t3.x, t3.y};
#pragma unroll
        for (int j = 0; j < 4; j++) {
            h2 s = gh[0] * w[j];
#pragma unroll
            for (int k = 1; k < 11; k++) s += gh[k] * w[j + k];
            ov[q][j] = s;
        }
    }
    const int gr0 = orow0 + (rp << 1);
#pragma unroll
    for (int j = 0; j < 4; j++) {
        const int gc = cb + j;
        if (gc < OW) {
#pragma unroll
            for (int r = 0; r < 2; r++) {
                const int gr = gr0 + r;
                if (gr < OH) {
                    float mu1 = r ? (float)ov[0][j].y : (float)ov[0][j].x;
                    float mu2 = r ? (float)ov[1][j].y : (float)ov[1][j].x;
                    float exx = r ? (float)ov[2][j].y : (float)ov[2][j].x;
                    float eyy = r ? (float)ov[3][j].y : (float)ov[3][j].x;
                    float exy = r ? (float)ov[4][j].y : (float)ov[4][j].x;
                    float mu1s = mu1 * mu1, mu2s = mu2 * mu2, mu12 = mu1 * mu2;
                    float s1v = exx - mu1s, s2v = eyy - mu2s, s12 = exy - mu12;
                    float num = (2.f * mu12 + C1V) * (2.f * s12 + C2V);
                    float den = (mu1s + mu2s + C1V) * (s1v + s2v + C2V);
                    lsum += num * __builtin_amdgcn_rcpf(den);
                }
            }
        }
    }
}

// one pair-step: input rows ir = O0+2S, ir+1 (depth-3 prefetch: preA/B/C)
template <int S>
__device__ __forceinline__ void stepf(
    float (&acc)[12][5], float& a0, float& a1, float& b1, float& d1,
    Pre& preA, Pre& preB, Pre& preC,
    const float* __restrict__ ytb, const float* __restrict__ ypb,
    int O0, int c, int cm, int cp, bool cgt0, bool clt511,
    const h2 (&rp)[10], const h2 (&gh)[11], float g0s, float g10s,
    h2 (*rbuf)[5][PADW], int tid, float& lsum) {
    Pre cur;
    if constexpr (S % 3 == 0) cur = preA;
    else if constexpr (S % 3 == 1) cur = preB;
    else cur = preC;
    // ---- issue loads for step S+3 (uniform row pointers -> SALU addressing) ----
    auto issue = [&](Pre& dst) {
        const int r1 = min(O0 + 2 * S + 7, IH - 1);
        const int r2 = min(O0 + 2 * S + 8, IH - 1);
        const int rE = min(O0 + 2 * S + 6, IH - 1);
        const float* pr1 = ytb + (size_t)r1 * IW;
        const float* pr2 = ytb + (size_t)r2 * IW;
        const float* pe0 = ypb + (size_t)rE * IW;
        const float* pe1 = ypb + (size_t)r1 * IW;
        dst.a2 = pr1[c];  dst.a3 = pr2[c];
        dst.b2 = pr1[cm]; dst.b3 = pr2[cm];
        dst.d2 = pr1[cp]; dst.d3 = pr2[cp];
        dst.e0 = pe0[c];  dst.e1 = pe1[c];
    };
    if constexpr (S + 3 <= LASTS) {
        if constexpr (S % 3 == 0) issue(preA);
        else if constexpr (S % 3 == 1) issue(preB);
        else issue(preC);
    }
    // ---- edge-enhance rows ir, ir+1 ----
    float lf0 = cgt0 ? b1 : 0.f;
    float rt0 = clt511 ? d1 : 0.f;
    float lf1 = cgt0 ? cur.b2 : 0.f;
    float rt1 = clt511 ? cur.d2 : 0.f;
    float xr0 = a0 + cur.a2 + lf0 + rt0 - 4.f * a1;
    float xr1 = a1 + cur.a3 + lf1 + rt1 - 4.f * cur.a2;
    float pr0[5] = {xr0, cur.e0, xr0 * xr0, cur.e0 * cur.e0, xr0 * cur.e0};
    float pr1[5] = {xr1, cur.e1, xr1 * xr1, cur.e1 * cur.e1, xr1 * cur.e1};
    h2 pk[5];
#pragma unroll
    for (int q = 0; q < 5; q++) pk[q] = pkrtz(pr0[q], pr1[q]);
    // ---- vertical ring: 2 taps per live output via fdot2 ----
    constexpr int RLO = (2 * S - 10 < 0) ? 0 : (2 * S - 10);
    constexpr int RHI = (2 * S + 1 > ROWS - 1) ? (ROWS - 1) : (2 * S + 1);
#pragma unroll
    for (int rel = RLO; rel <= RHI; ++rel) {
        const int k0 = 2 * S - rel;       // constant after unroll
        const int sl = rel % 12;
#pragma unroll
        for (int q = 0; q < 5; q++) {
            if (k0 == -1)
                acc[sl][q] = g0s * pr1[q];
            else if (k0 == 0)
                acc[sl][q] = __builtin_amdgcn_fdot2(rp[0], pk[q], 0.f, false);
            else if (k0 <= 9)
                acc[sl][q] = __builtin_amdgcn_fdot2(rp[k0], pk[q], acc[sl][q], false);
            else
                acc[sl][q] = fmaf(g10s, pr0[q], acc[sl][q]);
        }
    }
    // ---- carries ----
    a0 = cur.a2; a1 = cur.a3; b1 = cur.b3; d1 = cur.d3;
    // ---- emit completed row-pair (rel 2S-10, 2S-9) as packed half2 ----
    if constexpr (S >= 5) {
        constexpr int p2 = S - 5;
        constexpr int sl2 = p2 & 3;          // slot within 8-row phase
        constexpr int q0 = (2 * S - 10) % 12;
        constexpr int q1 = (2 * S - 9) % 12;
#pragma unroll
        for (int q = 0; q < 5; q++)
            rbuf[sl2][q][c] = pkrtz(acc[q0][q], acc[q1][q]);
    }
    // ---- 8-row phase at S = 8,12,16,20 (lgkm-only barriers; vmcnt in flight) ----
    if constexpr (S >= 8 && ((S - 8) % 4) == 0) {
        asm volatile("s_waitcnt lgkmcnt(0)\n\ts_barrier" ::: "memory");
        hphase8(rbuf, O0 + 8 * ((S - 8) / 4), tid, gh, lsum);
        if constexpr (S < LASTS)   // protect slot reuse by next emits
            asm volatile("s_waitcnt lgkmcnt(0)\n\ts_barrier" ::: "memory");
    }
}

template <int S, typename... A>
__device__ __forceinline__ void run_steps(A&... a) {
    stepf<S>(a...);
    if constexpr (S < LASTS) run_steps<S + 1>(a...);
}

__global__ __launch_bounds__(512) void ssim_stream(const float* __restrict__ yt,
                                                   const float* __restrict__ yp,
                                                   float* __restrict__ partial) {
    __shared__ __align__(16) h2 rbuf[4][5][PADW];   // ~41.9 KB, single-buffered
    __shared__ float wred[8];

    const int tid = threadIdx.x;
    const int c = tid;
    const int strip = blockIdx.x;
    const int img = blockIdx.y;
    const int O0 = strip * ROWS;
    const size_t ib = (size_t)img * (IH * IW);
    const float* ytb = yt + ib;
    const float* ypb = yp + ib;

    const int cm = c > 0 ? c - 1 : 0;
    const int cp = c < (IW - 1) ? c + 1 : (IW - 1);
    const bool cgt0 = c > 0, clt511 = c < (IW - 1);

    // zero the halo words 512..523 (read by cb>=500 threads, never emitted)
    if (tid < 240) {
        int sl = tid / 60, rem = tid % 60;
        int q = rem / 12, w = 512 + rem % 12;
        rbuf[sl][q][w] = h2{(_Float16)0.f, (_Float16)0.f};
    }

    // weights in registers (compile-time folded)
    h2 rp[10], gh[11];
#pragma unroll
    for (int k = 0; k < 10; k++) rp[k] = h2{(_Float16)GFc[k], (_Float16)GFc[k + 1]};
#pragma unroll
    for (int k = 0; k < 11; k++) gh[k] = h2{(_Float16)GFc[k], (_Float16)GFc[k]};
    const float g0s = GFc[0], g10s = GFc[10];

    // prologue: carries + first THREE steps' loads (uniform row pointers)
    float a0, a1, b1, d1;
    {
        const int rm1 = O0 > 0 ? O0 - 1 : 0;
        const float* pm1 = ytb + (size_t)rm1 * IW;
        const float* p0  = ytb + (size_t)O0 * IW;
        float a0v = pm1[c];
        a1 = p0[c]; b1 = p0[cm]; d1 = p0[cp];
        a0 = (O0 > 0) ? a0v : 0.f;
    }
    Pre preA, preB, preC;
    auto fill = [&](Pre& dst, int X) {
        const int r1 = min(O0 + 2 * X + 1, IH - 1);
        const int r2 = min(O0 + 2 * X + 2, IH - 1);
        const int rE = min(O0 + 2 * X,     IH - 1);
        const float* pr1 = ytb + (size_t)r1 * IW;
        const float* pr2 = ytb + (size_t)r2 * IW;
        const float* pe0 = ypb + (size_t)rE * IW;
        const float* pe1 = ypb + (size_t)r1 * IW;
        dst.a2 = pr1[c];  dst.a3 = pr2[c];
        dst.b2 = pr1[cm]; dst.b3 = pr2[cm];
        dst.d2 = pr1[cp]; dst.d3 = pr2[cp];
        dst.e0 = pe0[c];  dst.e1 = pe1[c];
    };
    fill(preA, 0);
    fill(preB, 1);
    fill(preC, 2);

    float acc[12][5];   // ring; every slot is init-on-first-tap
    float lsum = 0.f;

    run_steps<0>(acc, a0, a1, b1, d1, preA, preB, preC, ytb, ypb, O0,
                 c, cm, cp, cgt0, clt511, rp, gh, g0s, g10s, rbuf, tid, lsum);

#pragma unroll
    for (int off = 32; off > 0; off >>= 1) lsum += __shfl_down(lsum, off);
    if ((tid & 63) == 0) wred[tid >> 6] = lsum;
    __syncthreads();
    if (tid == 0) {
        float s = 0.f;
#pragma unroll
        for (int w = 0; w < 8; w++) s += wred[w];
        partial[strip + NSTRIP * img] = s;
    }
}

__global__ __launch_bounds__(256) void ssim_final(const float* __restrict__ partial,
                                                  float* __restrict__ out) {
    __shared__ double wred[4];
    double s = 0.0;
    for (int i = threadIdx.x; i < NBLK; i += 256) s += (double)partial[i];
#pragma unroll
    for (int off = 32; off > 0; off >>= 1) s += __shfl_down(s, off);
    if ((threadIdx.x & 63) == 0) wred[threadIdx.x >> 6] = s;
    __syncthreads();
    if (threadIdx.x == 0) {
        double tot = wred[0] + wred[1] + wred[2] + wred[3];
        out[0] = (float)(1.0 - tot / (double)((long long)OH * OW * NIMG));
    }
}

extern "C" void kernel_launch(void* const* d_in, const int* in_sizes, int n_in,
                              void* d_out, int out_size, void* d_ws, size_t ws_size,
                              hipStream_t stream) {
    const float* yt = (const float*)d_in[0];
    const float* yp = (const float*)d_in[1];
    float* out = (float*)d_out;
    float* partial = (float*)d_ws;   // NBLK floats = 3 KB

    dim3 grid(NSTRIP, NIMG);
    hipLaunchKernelGGL(ssim_stream, grid, dim3(512), 0, stream, yt, yp, partial);
    hipLaunchKernelGGL(ssim_final, dim3(1), dim3(256), 0, stream, partial, out);
}

// Round 9
// 45.205 us; speedup vs baseline: 1.9293x; 1.2313x over previous
//
#include <hip/hip_runtime.h>

typedef _Float16 h2 __attribute__((ext_vector_type(2)));

#define IH 512
#define IW 512
#define OH 502
#define OW 502
#define NIMG 48
#define ROWS 32
#define NSTRIP 16                 // 16*32 = 512 >= 502
#define NBLK (NSTRIP * NIMG)      // 768
#define PADW 524                  // h2 words per rowbuf row; 524*4B = 2096 % 16 == 0
#define LASTS 20                  // pair-steps S = 0..20 (42 input rows)
#define C1V 1.0e-4f
#define C2V 9.0e-4f

// gaussian(win=11, sigma=1.5), normalized
constexpr float GFc[11] = {
    0.00102838f, 0.00759876f, 0.03600078f, 0.10936070f, 0.21300554f,
    0.26601173f, 0.21300554f, 0.10936070f, 0.03600078f, 0.00759876f,
    0.00102838f};

// cvt_pkrtz returns __fp16-vec; bit-cast to our _Float16-vec h2 (same layout)
static __device__ __forceinline__ h2 pkrtz(float a, float b) {
    return __builtin_bit_cast(h2, __builtin_amdgcn_cvt_pkrtz(a, b));
}

// force a packed-f16 constant into an SGPR (VOP3P has no packed literals;
// fdot2 / v_pk_* legally take 1 SGPR source -> no per-use remat, -VGPR)
static __device__ __forceinline__ h2 sgpr_h2(float a, float b) {
    h2 v = h2{(_Float16)a, (_Float16)b};
    int i = __builtin_amdgcn_readfirstlane(__builtin_bit_cast(int, v));
    return __builtin_bit_cast(h2, i);
}

struct SC { h2 c1, c2, two, one; };   // SGPR-resident h2 constants

struct Pre {  // pipelined loads for one pair-step
    float a2, a3;   // yt col c,   rows 2X+1, 2X+2
    float b2, b3;   // yt col c-1, rows 2X+1, 2X+2
    float d2, d3;   // yt col c+1, rows 2X+1, 2X+2
    float e0, e1;   // yp col c,   rows 2X,   2X+1
};

template <int M>
__device__ __forceinline__ Pre& pick(Pre& A, Pre& B, Pre& C) {
    if constexpr (M == 0) return A;
    else if constexpr (M == 1) return B;
    else return C;
}

struct __align__(16) H4  { h2 a, b, c, d; };
struct __align__(8)  H22 { h2 x, y; };

// 8-row H-phase: thread -> (row-pair rp = tid>>7, out cols cb..cb+3).
// 14 aligned words per q (3x b128 + 1x b64); packed 11-tap blur; packed SSIM
// with branchless mask folding; f32 only for the final rcp+accumulate.
__device__ __forceinline__ void hphase8(const h2 (*rb)[5][PADW], int orow0,
                                        int tid, const h2 (&gh)[11], const SC& sc,
                                        float& lsum) {
    const int rp = tid >> 7;             // pair-slot 0..3
    const int cb = (tid & 127) << 2;     // out-col base 0..508 (16B aligned)
    h2 ov[5][4];                         // packed (row-even, row-odd) per q, col
#pragma unroll
    for (int q = 0; q < 5; q++) {
        const h2* rowp = &rb[rp][q][cb];
        H4  t0 = *(const H4*)(rowp);
        H4  t1 = *(const H4*)(rowp + 4);
        H4  t2 = *(const H4*)(rowp + 8);
        H22 t3 = *(const H22*)(rowp + 12);
        h2 w[14] = {t0.a, t0.b, t0.c, t0.d, t1.a, t1.b, t1.c, t1.d,
                    t2.a, t2.b, t2.c, t2.d, t3.x, t3.y};
#pragma unroll
        for (int j = 0; j < 4; j++) {
            h2 s = gh[0] * w[j];
#pragma unroll
            for (int k = 1; k < 11; k++) s += gh[k] * w[j + k];
            ov[q][j] = s;
        }
    }
    const int gr0 = orow0 + (rp << 1);
    const h2 zero = h2{(_Float16)0.f, (_Float16)0.f};
    const h2 mrow = pkrtz(gr0 < OH ? 1.f : 0.f, gr0 + 1 < OH ? 1.f : 0.f);
#pragma unroll
    for (int j = 0; j < 4; j++) {
        const h2 mk = (cb + j < OW) ? mrow : zero;
        const h2 iv = sc.one - mk;
        h2 mu1 = ov[0][j], mu2 = ov[1][j];
        h2 exx = ov[2][j], eyy = ov[3][j], exy = ov[4][j];
        h2 mu1s = mu1 * mu1, mu2s = mu2 * mu2, mu12 = mu1 * mu2;
        h2 s1v = exx - mu1s, s2v = eyy - mu2s, s12 = exy - mu12;
        h2 num = (mu12 * sc.two + sc.c1) * (s12 * sc.two + sc.c2);
        h2 den = (mu1s + mu2s + sc.c1) * (s1v + s2v + sc.c2);
        num = num * mk;
        den = den * mk + iv;          // masked lanes: den=1, num=0 (no inf/NaN)
        float nlo = (float)num.x, nhi = (float)num.y;
        float dlo = (float)den.x, dhi = (float)den.y;
        lsum += nlo * __builtin_amdgcn_rcpf(dlo);
        lsum += nhi * __builtin_amdgcn_rcpf(dhi);
    }
}

// one pair-step: input rows ir = O0+2S, ir+1 (depth-3 prefetch, in-place buffer)
template <int S>
__device__ __forceinline__ void stepf(
    float (&acc)[12][5], float& a0, float& a1, float& b1, float& d1,
    Pre& preA, Pre& preB, Pre& preC,
    const float* __restrict__ ytb, const float* __restrict__ ypb,
    int O0, int c, int cm, int cp, bool cgt0, bool clt511,
    const h2 (&rp)[10], const h2 (&gh)[11], const SC& sc, float g0s, float g10s,
    h2 (*rbuf)[5][PADW], int tid, float& lsum) {
    Pre& cur = pick<S % 3>(preA, preB, preC);
    // ---- consume cur first (reference, no copy): edge-enhance rows ir, ir+1 ----
    float lf0 = cgt0 ? b1 : 0.f;
    float rt0 = clt511 ? d1 : 0.f;
    float lf1 = cgt0 ? cur.b2 : 0.f;
    float rt1 = clt511 ? cur.d2 : 0.f;
    float xr0 = a0 + cur.a2 + lf0 + rt0 - 4.f * a1;
    float xr1 = a1 + cur.a3 + lf1 + rt1 - 4.f * cur.a2;
    float pr0[5] = {xr0, cur.e0, xr0 * xr0, cur.e0 * cur.e0, xr0 * cur.e0};
    float pr1[5] = {xr1, cur.e1, xr1 * xr1, cur.e1 * cur.e1, xr1 * cur.e1};
    h2 pk[5];
#pragma unroll
    for (int q = 0; q < 5; q++) pk[q] = pkrtz(pr0[q], pr1[q]);
    // carries (all cur reads complete before the buffer is reused)
    a0 = cur.a2; a1 = cur.a3; b1 = cur.b3; d1 = cur.d3;
    // ---- issue loads for step S+3 into cur (uniform row ptrs -> SALU addr) ----
    if constexpr (S + 3 <= LASTS) {
        const int r1 = min(O0 + 2 * S + 7, IH - 1);
        const int r2 = min(O0 + 2 * S + 8, IH - 1);
        const int rE = min(O0 + 2 * S + 6, IH - 1);
        const float* pr1p = ytb + (size_t)r1 * IW;
        const float* pr2p = ytb + (size_t)r2 * IW;
        const float* pe0p = ypb + (size_t)rE * IW;
        const float* pe1p = ypb + (size_t)r1 * IW;
        cur.a2 = pr1p[c];  cur.a3 = pr2p[c];
        cur.b2 = pr1p[cm]; cur.b3 = pr2p[cm];
        cur.d2 = pr1p[cp]; cur.d3 = pr2p[cp];
        cur.e0 = pe0p[c];  cur.e1 = pe1p[c];
    }
    // ---- vertical ring: 2 taps per live output via fdot2 (SGPR weights) ----
    constexpr int RLO = (2 * S - 10 < 0) ? 0 : (2 * S - 10);
    constexpr int RHI = (2 * S + 1 > ROWS - 1) ? (ROWS - 1) : (2 * S + 1);
#pragma unroll
    for (int rel = RLO; rel <= RHI; ++rel) {
        const int k0 = 2 * S - rel;       // constant after unroll
        const int sl = rel % 12;
#pragma unroll
        for (int q = 0; q < 5; q++) {
            if (k0 == -1)
                acc[sl][q] = g0s * pr1[q];
            else if (k0 == 0)
                acc[sl][q] = __builtin_amdgcn_fdot2(rp[0], pk[q], 0.f, false);
            else if (k0 <= 9)
                acc[sl][q] = __builtin_amdgcn_fdot2(rp[k0], pk[q], acc[sl][q], false);
            else
                acc[sl][q] = fmaf(g10s, pr0[q], acc[sl][q]);
        }
    }
    // ---- emit completed row-pair (rel 2S-10, 2S-9) as packed half2 ----
    if constexpr (S >= 5) {
        constexpr int p2 = S - 5;
        constexpr int sl2 = p2 & 3;          // slot within 8-row phase
        constexpr int q0 = (2 * S - 10) % 12;
        constexpr int q1 = (2 * S - 9) % 12;
#pragma unroll
        for (int q = 0; q < 5; q++)
            rbuf[sl2][q][c] = pkrtz(acc[q0][q], acc[q1][q]);
    }
    // ---- 8-row phase at S = 8,12,16,20 (lgkm-only barriers; vmcnt in flight) ----
    if constexpr (S >= 8 && ((S - 8) % 4) == 0) {
        asm volatile("s_waitcnt lgkmcnt(0)\n\ts_barrier" ::: "memory");
        hphase8(rbuf, O0 + 8 * ((S - 8) / 4), tid, gh, sc, lsum);
        if constexpr (S < LASTS)   // protect slot reuse by next emits
            asm volatile("s_waitcnt lgkmcnt(0)\n\ts_barrier" ::: "memory");
    }
}

template <int S, typename... A>
__device__ __forceinline__ void run_steps(A&... a) {
    stepf<S>(a...);
    if constexpr (S < LASTS) run_steps<S + 1>(a...);
}

__global__ __launch_bounds__(512) void ssim_stream(const float* __restrict__ yt,
                                                   const float* __restrict__ yp,
                                                   float* __restrict__ partial) {
    __shared__ __align__(16) h2 rbuf[4][5][PADW];   // ~41.9 KB, single-buffered
    __shared__ float wred[8];

    const int tid = threadIdx.x;
    const int c = tid;
    const int strip = blockIdx.x;
    const int img = blockIdx.y;
    const int O0 = strip * ROWS;
    const size_t ib = (size_t)img * (IH * IW);
    const float* ytb = yt + ib;
    const float* ypb = yp + ib;

    const int cm = c > 0 ? c - 1 : 0;
    const int cp = c < (IW - 1) ? c + 1 : (IW - 1);
    const bool cgt0 = c > 0, clt511 = c < (IW - 1);

    // zero the halo words 512..523 (read by cb>=500 threads, never emitted)
    if (tid < 240) {
        int sl = tid / 60, rem = tid % 60;
        int q = rem / 12, w = 512 + rem % 12;
        rbuf[sl][q][w] = h2{(_Float16)0.f, (_Float16)0.f};
    }

    // weights + constants in SGPRs (1 SGPR src legal for fdot2 / v_pk_*)
    h2 rp[10], gh[11];
#pragma unroll
    for (int k = 0; k < 10; k++) rp[k] = sgpr_h2(GFc[k], GFc[k + 1]);
#pragma unroll
    for (int k = 0; k < 11; k++) gh[k] = sgpr_h2(GFc[k], GFc[k]);
    const SC sc = {sgpr_h2(C1V, C1V), sgpr_h2(C2V, C2V),
                   sgpr_h2(2.f, 2.f), sgpr_h2(1.f, 1.f)};
    const float g0s = GFc[0], g10s = GFc[10];

    // prologue: carries + first THREE steps' loads (uniform row pointers)
    float a0, a1, b1, d1;
    {
        const int rm1 = O0 > 0 ? O0 - 1 : 0;
        const float* pm1 = ytb + (size_t)rm1 * IW;
        const float* p0  = ytb + (size_t)O0 * IW;
        float a0v = pm1[c];
        a1 = p0[c]; b1 = p0[cm]; d1 = p0[cp];
        a0 = (O0 > 0) ? a0v : 0.f;
    }
    Pre preA, preB, preC;
    auto fill = [&](Pre& dst, int X) {
        const int r1 = min(O0 + 2 * X + 1, IH - 1);
        const int r2 = min(O0 + 2 * X + 2, IH - 1);
        const int rE = min(O0 + 2 * X,     IH - 1);
        const float* pr1p = ytb + (size_t)r1 * IW;
        const float* pr2p = ytb + (size_t)r2 * IW;
        const float* pe0p = ypb + (size_t)rE * IW;
        const float* pe1p = ypb + (size_t)r1 * IW;
        dst.a2 = pr1p[c];  dst.a3 = pr2p[c];
        dst.b2 = pr1p[cm]; dst.b3 = pr2p[cm];
        dst.d2 = pr1p[cp]; dst.d3 = pr2p[cp];
        dst.e0 = pe0p[c];  dst.e1 = pe1p[c];
    };
    fill(preA, 0);
    fill(preB, 1);
    fill(preC, 2);

    float acc[12][5];   // ring; every slot is init-on-first-tap
    float lsum = 0.f;

    run_steps<0>(acc, a0, a1, b1, d1, preA, preB, preC, ytb, ypb, O0,
                 c, cm, cp, cgt0, clt511, rp, gh, sc, g0s, g10s, rbuf, tid, lsum);

#pragma unroll
    for (int off = 32; off > 0; off >>= 1) lsum += __shfl_down(lsum, off);
    if ((tid & 63) == 0) wred[tid >> 6] = lsum;
    __syncthreads();
    if (tid == 0) {
        float s = 0.f;
#pragma unroll
        for (int w = 0; w < 8; w++) s += wred[w];
        partial[strip + NSTRIP * img] = s;
    }
}

__global__ __launch_bounds__(256) void ssim_final(const float* __restrict__ partial,
                                                  float* __restrict__ out) {
    __shared__ double wred[4];
    double s = 0.0;
    for (int i = threadIdx.x; i < NBLK; i += 256) s += (double)partial[i];
#pragma unroll
    for (int off = 32; off > 0; off >>= 1) s += __shfl_down(s, off);
    if ((threadIdx.x & 63) == 0) wred[threadIdx.x >> 6] = s;
    __syncthreads();
    if (threadIdx.x == 0) {
        double tot = wred[0] + wred[1] + wred[2] + wred[3];
        out[0] = (float)(1.0 - tot / (double)((long long)OH * OW * NIMG));
    }
}

extern "C" void kernel_launch(void* const* d_in, const int* in_sizes, int n_in,
                              void* d_out, int out_size, void* d_ws, size_t ws_size,
                              hipStream_t stream) {
    const float* yt = (const float*)d_in[0];
    const float* yp = (const float*)d_in[1];
    float* out = (float*)d_out;
    float* partial = (float*)d_ws;   // NBLK floats = 3 KB

    dim3 grid(NSTRIP, NIMG);
    hipLaunchKernelGGL(ssim_stream, grid, dim3(512), 0, stream, yt, yp, partial);
    hipLaunchKernelGGL(ssim_final, dim3(1), dim3(256), 0, stream, partial, out);
}